// Round 1
// 68.916 us; speedup vs baseline: 1.0828x; 1.0828x over previous
//
#include <hip/hip_runtime.h>

#define B_SZ 16
#define N_BOX 2048
#define AH 256
#define AW 256
#define ROWS 8                 // rows per block -> 32 strips/batch, 512 blocks
#define NBLK (B_SZ * (AH / ROWS))   // 512

// ---------------------------------------------------------------------------
// Kernel 1: per-(batch, 8-row-strip) block. Scans all 2048 boxes with three
// unconditional float2 loads per box (removes the dependent scalar-load ->
// branch -> scalar-load chain), compacts survivors into LDS, builds per-column
// coverage bits, fused BCE over the strip's 8 coalesced rows, block tree
// reduction -> ONE plain store of the partial into d_ws[blockIdx.x].
// No atomics, no pre-zeroed output needed: every slot is written every run.
// Kernel 2: single block tree-reduces the 512 partials into out[0].
// ---------------------------------------------------------------------------
__global__ __launch_bounds__(256) void fused_kernel(
    const float* __restrict__ target,   // [N_BOX, 6]
    const float* __restrict__ mask,     // [B_SZ,1,AH,AW]
    const int*   __restrict__ img_h_p,
    const int*   __restrict__ img_w_p,
    float*       __restrict__ partial)  // [NBLK] in d_ws
{
    const int b  = blockIdx.x >> 5;            // 32 strips per batch
    const int y0 = (blockIdx.x & 31) * ROWS;
    const int x  = threadIdx.x;

    __shared__ unsigned s_list[N_BOX];         // packed (X1, X2, rowbits)
    __shared__ int   s_n;
    __shared__ int   s_has;
    __shared__ float s_red[4];

    if (x == 0) { s_n = 0; s_has = 0; }
    __syncthreads();

    const float fh = (float)img_h_p[0];
    const float fw = (float)img_w_p[0];
    const float sx = (float)AW / fw;
    const float sy = (float)AH / fh;

    for (int base = 0; base < N_BOX; base += 256) {
        // target row stride = 24 B, always 8 B aligned -> three float2 loads
        const float2* tp = (const float2*)(target + (size_t)(base + x) * 6);
        const float2 t01 = tp[0];              // (bidx, cls)
        const float2 t23 = tp[1];              // (xc, yc)
        const float2 t45 = tp[2];              // (bw, bh)
        const int bi = (int)t01.x;
        if (bi == b) {
            s_has = 1;                          // all writers store 1: race-free
            const float xc = t23.x, yc = t23.y, bw = t45.x, bh = t45.y;
            // exact replication of reference float32 math
            const float x1 = fw * (xc - bw * 0.5f);
            const float y1 = fh * (yc - bh * 0.5f);
            const float x2 = fw * (xc + bw * 0.5f);
            const float y2 = fh * (yc + bh * 0.5f);
            const bool valid = (x1 <= fw) && (y1 <= fh) &&
                               (x2 <= fw) && (y2 <= fh);
            const int X1 = (int)fmaxf(truncf(x1 * sx), 0.0f);
            const int Y1 = (int)fmaxf(truncf(y1 * sy), 0.0f);
            const int X2 = (int)fminf(ceilf(x2 * sx) + 1.0f, (float)AW);
            const int Y2 = (int)fminf(ceilf(y2 * sy) + 1.0f, (float)AH);
            if (valid && X1 < X2 && Y1 < y0 + ROWS && Y2 > y0) {
                const int lo = max(Y1 - y0, 0);
                const int hi = min(Y2 - y0, ROWS);
                const unsigned rowbits = ((1u << (hi - lo)) - 1u) << lo;
                const unsigned entry = (unsigned)X1 | ((unsigned)X2 << 9)
                                     | (rowbits << 18);
                s_list[atomicAdd(&s_n, 1)] = entry;
            }
        }
    }
    __syncthreads();

    // coverage OR over the compacted list (order-independent -> deterministic)
    const int n = s_n;
    unsigned cov = 0;                           // bit r: pixel (y0+r, x)
    for (int j = 0; j < n; ++j) {
        const unsigned e = s_list[j];           // LDS broadcast (same addr)
        const int X1 = (int)(e & 511u);
        const int X2 = (int)((e >> 9) & 511u);
        cov |= (x >= X1 && x < X2) ? (e >> 18) : 0u;
    }

    float acc = 0.0f;
    #pragma unroll
    for (int r = 0; r < ROWS; ++r) {
        const float l = mask[((size_t)b * AH + (y0 + r)) * AW + x];
        const float m = (float)((cov >> r) & 1u);
        acc += fmaxf(l, 0.0f) - l * m + log1pf(expf(-fabsf(l)));
    }

    // wave (64-lane) shuffle reduction, then cross-wave via LDS
    #pragma unroll
    for (int off = 32; off > 0; off >>= 1) acc += __shfl_down(acc, off, 64);
    if ((x & 63) == 0) s_red[x >> 6] = acc;
    __syncthreads();
    if (x == 0) {
        const float sum = (s_red[0] + s_red[1] + s_red[2] + s_red[3])
                        * (1.0f / (float)(AH * AW));
        partial[blockIdx.x] = s_has ? sum : 0.0f;   // plain store, no atomic
    }
}

__global__ __launch_bounds__(256) void reduce_kernel(
    const float* __restrict__ partial,   // [NBLK]
    float*       __restrict__ out)       // [1]
{
    const int x = threadIdx.x;
    float a = partial[x] + partial[x + 256];
    #pragma unroll
    for (int off = 32; off > 0; off >>= 1) a += __shfl_down(a, off, 64);
    __shared__ float r[4];
    if ((x & 63) == 0) r[x >> 6] = a;
    __syncthreads();
    if (x == 0) out[0] = r[0] + r[1] + r[2] + r[3];
}

extern "C" void kernel_launch(void* const* d_in, const int* in_sizes, int n_in,
                              void* d_out, int out_size, void* d_ws, size_t ws_size,
                              hipStream_t stream) {
    const float* attention_mask = (const float*)d_in[0];
    const float* target         = (const float*)d_in[1];
    const int*   img_h          = (const int*)d_in[3];
    const int*   img_w          = (const int*)d_in[4];
    float*       partial        = (float*)d_ws;
    float*       out            = (float*)d_out;

    fused_kernel<<<NBLK, 256, 0, stream>>>(
        target, attention_mask, img_h, img_w, partial);
    reduce_kernel<<<1, 256, 0, stream>>>(partial, out);
}